// Round 2
// baseline (13065.718 us; speedup 1.0000x reference)
//
#include <hip/hip_runtime.h>
#include <math.h>

// Problem constants
#define BB 128
#define TT 512
#define DD 256
#define HH 256
#define NG 1024  // 4*H

__device__ __forceinline__ float sigmoidf_(float x) {
    return 1.0f / (1.0f + __expf(-x));
}
__device__ __forceinline__ float tanhf_(float x) {
    x = fminf(15.0f, fmaxf(-15.0f, x));
    float e = __expf(2.0f * x);
    return (e - 1.0f) / (e + 1.0f);
}
__device__ __forceinline__ void fma4(float4& a, const float4& b, float s) {
    a.x += b.x * s; a.y += b.y * s; a.z += b.z * s; a.w += b.w * s;
}

// Pack weights into gate-interleaved layouts.
// packed index n = j*4 + q  <->  gate row g = q*256 + j   (q: 0=i,1=f,2=g,3=o)
//   Wp_ih  [n, k]    (row-major, for the GEMM)
//   Wp_ih_t[k, n]    (k-major, for fused fallback)
//   Wp_hh_t[k, n]    (k-major, for the recurrence)
//   bias_p [n] = b_ih[g] + b_hh[g]
__global__ void pack_weights(const float* __restrict__ W_ih, const float* __restrict__ W_hh,
                             const float* __restrict__ b_ih, const float* __restrict__ b_hh,
                             float* __restrict__ Wp_ih, float* __restrict__ Wp_ih_t,
                             float* __restrict__ Wp_hh_t, float* __restrict__ bias_p) {
    int idx = blockIdx.x * 256 + threadIdx.x;   // 0 .. 262143
    int n = idx >> 8;
    int k = idx & 255;
    int j = n >> 2, q = n & 3;
    int g = q * 256 + j;
    float wih = W_ih[g * 256 + k];
    float whh = W_hh[g * 256 + k];
    Wp_ih[n * 256 + k] = wih;
    Wp_ih_t[k * 1024 + n] = wih;
    Wp_hh_t[k * 1024 + n] = whh;
    if (idx < 1024) {
        int nn = idx, jj = nn >> 2, qq = nn & 3;
        int gg = qq * 256 + jj;
        bias_p[nn] = b_ih[gg] + b_hh[gg];
    }
}

// xg[m, n] = dot(x[m, :], Wp_ih[n, :]) + bias_p[n]
// M = B*T = 65536, N = 1024, K = 256. Tiled fp32: BM=BN=64, BK=16, 256 thr, 4x4/thr.
__global__ __launch_bounds__(256) void xg_gemm(const float* __restrict__ X,
                                               const float* __restrict__ Wp,
                                               const float* __restrict__ bias_p,
                                               float* __restrict__ xg) {
    __shared__ float As[16][68];  // [k][m], pad to 68 (16B-aligned rows, no pow2 stride)
    __shared__ float Bs[16][68];  // [k][n]
    int tid = threadIdx.x;
    int m0 = blockIdx.x * 64;
    int n0 = blockIdx.y * 64;
    int row = tid >> 2, kq = tid & 3;     // staging: 64 rows x 4 float4
    int tx = tid & 15, ty = tid >> 4;     // compute: 16x16 threads, 4x4 each
    float acc[4][4];
#pragma unroll
    for (int i = 0; i < 4; ++i)
#pragma unroll
        for (int j = 0; j < 4; ++j) acc[i][j] = 0.0f;

    for (int k0 = 0; k0 < 256; k0 += 16) {
        float4 a = *(const float4*)&X[(size_t)(m0 + row) * 256 + k0 + kq * 4];
        float4 b = *(const float4*)&Wp[(size_t)(n0 + row) * 256 + k0 + kq * 4];
        __syncthreads();
        As[kq * 4 + 0][row] = a.x; As[kq * 4 + 1][row] = a.y;
        As[kq * 4 + 2][row] = a.z; As[kq * 4 + 3][row] = a.w;
        Bs[kq * 4 + 0][row] = b.x; Bs[kq * 4 + 1][row] = b.y;
        Bs[kq * 4 + 2][row] = b.z; Bs[kq * 4 + 3][row] = b.w;
        __syncthreads();
#pragma unroll
        for (int k = 0; k < 16; ++k) {
            float4 ra = *(const float4*)&As[k][ty * 4];
            float4 rb = *(const float4*)&Bs[k][tx * 4];
            float va[4] = {ra.x, ra.y, ra.z, ra.w};
            float vb[4] = {rb.x, rb.y, rb.z, rb.w};
#pragma unroll
            for (int i = 0; i < 4; ++i)
#pragma unroll
                for (int j = 0; j < 4; ++j) acc[i][j] += va[i] * vb[j];
        }
    }
    float4 bias = *(const float4*)&bias_p[n0 + tx * 4];
#pragma unroll
    for (int i = 0; i < 4; ++i) {
        float4 v;
        v.x = acc[i][0] + bias.x; v.y = acc[i][1] + bias.y;
        v.z = acc[i][2] + bias.z; v.w = acc[i][3] + bias.w;
        *(float4*)&xg[(size_t)(m0 + ty * 4 + i) * 1024 + n0 + tx * 4] = v;
    }
}

// Recurrence: 64 blocks x 256 threads, 2 samples per block (amortize the W_hh
// L2 stream over 2 samples). Thread tid owns h-column tid for both samples;
// per k it fetches float4 Wp_hh_t[k][tid*4..] = (i,f,g,o) weights for its column.
__global__ __launch_bounds__(256) void lstm_rec(const float* __restrict__ xg,
                                                const float* __restrict__ Wp_hh_t,
                                                const int* __restrict__ x_len,
                                                float* __restrict__ out) {
    __shared__ float hA[256], hB[256];
    int tid = threadIdx.x;
    int b0 = blockIdx.x * 2, b1 = b0 + 1;
    hA[tid] = 0.0f; hB[tid] = 0.0f;
    float cA = 0.0f, cB = 0.0f;
    int lenA = x_len[b0], lenB = x_len[b1];
    __syncthreads();

    for (int t = 0; t < TT; ++t) {
        const float4* gA = (const float4*)(xg + ((size_t)b0 * TT + t) * 1024);
        const float4* gB = (const float4*)(xg + ((size_t)b1 * TT + t) * 1024);
        float4 accA = gA[tid];
        float4 accB = gB[tid];
#pragma unroll 4
        for (int k = 0; k < 256; k += 4) {
            float4 ha = *(const float4*)&hA[k];
            float4 hb = *(const float4*)&hB[k];
            const float4* Wk = (const float4*)(Wp_hh_t + (size_t)k * 1024);
            float4 w0 = Wk[tid];
            float4 w1 = Wk[256 + tid];
            float4 w2 = Wk[512 + tid];
            float4 w3 = Wk[768 + tid];
            fma4(accA, w0, ha.x); fma4(accB, w0, hb.x);
            fma4(accA, w1, ha.y); fma4(accB, w1, hb.y);
            fma4(accA, w2, ha.z); fma4(accB, w2, hb.z);
            fma4(accA, w3, ha.w); fma4(accB, w3, hb.w);
        }
        float iA = sigmoidf_(accA.x), fA = sigmoidf_(accA.y);
        float gA_ = tanhf_(accA.z),  oA = sigmoidf_(accA.w);
        cA = fA * cA + iA * gA_;
        float hnA = oA * tanhf_(cA);
        float iB = sigmoidf_(accB.x), fB = sigmoidf_(accB.y);
        float gB_ = tanhf_(accB.z),  oB = sigmoidf_(accB.w);
        cB = fB * cB + iB * gB_;
        float hnB = oB * tanhf_(cB);

        __syncthreads();            // all reads of hA/hB done
        hA[tid] = hnA; hB[tid] = hnB;
        out[((size_t)b0 * TT + t) * HH + tid] = (t < lenA) ? hnA : 0.0f;
        out[((size_t)b1 * TT + t) * HH + tid] = (t < lenB) ? hnB : 0.0f;
        __syncthreads();            // writes visible before next iter reads
    }
}

// Fallback if ws too small to materialize xg: recompute x-projection per step.
__global__ __launch_bounds__(256) void lstm_rec_fused(const float* __restrict__ X,
                                                      const float* __restrict__ Wp_ih_t,
                                                      const float* __restrict__ Wp_hh_t,
                                                      const float* __restrict__ bias_p,
                                                      const int* __restrict__ x_len,
                                                      float* __restrict__ out) {
    __shared__ float hA[256], hB[256], xsA[256], xsB[256];
    int tid = threadIdx.x;
    int b0 = blockIdx.x * 2, b1 = b0 + 1;
    hA[tid] = 0.0f; hB[tid] = 0.0f;
    float cA = 0.0f, cB = 0.0f;
    int lenA = x_len[b0], lenB = x_len[b1];
    float4 bias = *(const float4*)&bias_p[tid * 4];

    for (int t = 0; t < TT; ++t) {
        __syncthreads();  // previous-iter h writes + xs reuse safe
        xsA[tid] = X[((size_t)b0 * TT + t) * DD + tid];
        xsB[tid] = X[((size_t)b1 * TT + t) * DD + tid];
        __syncthreads();
        float4 accA = bias, accB = bias;
#pragma unroll 4
        for (int k = 0; k < 256; k += 4) {
            float4 xa = *(const float4*)&xsA[k];
            float4 xb = *(const float4*)&xsB[k];
            const float4* Wk = (const float4*)(Wp_ih_t + (size_t)k * 1024);
            float4 w0 = Wk[tid];
            float4 w1 = Wk[256 + tid];
            float4 w2 = Wk[512 + tid];
            float4 w3 = Wk[768 + tid];
            fma4(accA, w0, xa.x); fma4(accB, w0, xb.x);
            fma4(accA, w1, xa.y); fma4(accB, w1, xb.y);
            fma4(accA, w2, xa.z); fma4(accB, w2, xb.z);
            fma4(accA, w3, xa.w); fma4(accB, w3, xb.w);
        }
#pragma unroll 4
        for (int k = 0; k < 256; k += 4) {
            float4 ha = *(const float4*)&hA[k];
            float4 hb = *(const float4*)&hB[k];
            const float4* Wk = (const float4*)(Wp_hh_t + (size_t)k * 1024);
            float4 w0 = Wk[tid];
            float4 w1 = Wk[256 + tid];
            float4 w2 = Wk[512 + tid];
            float4 w3 = Wk[768 + tid];
            fma4(accA, w0, ha.x); fma4(accB, w0, hb.x);
            fma4(accA, w1, ha.y); fma4(accB, w1, hb.y);
            fma4(accA, w2, ha.z); fma4(accB, w2, hb.z);
            fma4(accA, w3, ha.w); fma4(accB, w3, hb.w);
        }
        float iA = sigmoidf_(accA.x), fA = sigmoidf_(accA.y);
        float gA_ = tanhf_(accA.z),  oA = sigmoidf_(accA.w);
        cA = fA * cA + iA * gA_;
        float hnA = oA * tanhf_(cA);
        float iB = sigmoidf_(accB.x), fB = sigmoidf_(accB.y);
        float gB_ = tanhf_(accB.z),  oB = sigmoidf_(accB.w);
        cB = fB * cB + iB * gB_;
        float hnB = oB * tanhf_(cB);

        __syncthreads();
        hA[tid] = hnA; hB[tid] = hnB;
        out[((size_t)b0 * TT + t) * HH + tid] = (t < lenA) ? hnA : 0.0f;
        out[((size_t)b1 * TT + t) * HH + tid] = (t < lenB) ? hnB : 0.0f;
    }
}

extern "C" void kernel_launch(void* const* d_in, const int* in_sizes, int n_in,
                              void* d_out, int out_size, void* d_ws, size_t ws_size,
                              hipStream_t stream) {
    const float* x     = (const float*)d_in[0];
    const int*   x_len = (const int*)d_in[1];
    const float* W_ih  = (const float*)d_in[2];
    const float* W_hh  = (const float*)d_in[3];
    const float* b_ih  = (const float*)d_in[4];
    const float* b_hh  = (const float*)d_in[5];
    float* out = (float*)d_out;

    char* ws = (char*)d_ws;
    float* Wp_ih   = (float*)(ws);                         // 1 MB
    float* Wp_hh_t = (float*)(ws + (1u << 20));            // 1 MB
    float* Wp_ih_t = (float*)(ws + (2u << 20));            // 1 MB
    float* bias_p  = (float*)(ws + (3u << 20));            // 4 KB
    float* xg      = (float*)(ws + (3u << 20) + 4096);     // 268.4 MB
    size_t need_full = (size_t)(3u << 20) + 4096 + (size_t)BB * TT * NG * 4;
    bool full = ws_size >= need_full;

    pack_weights<<<1024, 256, 0, stream>>>(W_ih, W_hh, b_ih, b_hh,
                                           Wp_ih, Wp_ih_t, Wp_hh_t, bias_p);
    if (full) {
        dim3 grid(BB * TT / 64, NG / 64);   // 1024 x 16
        xg_gemm<<<grid, 256, 0, stream>>>(x, Wp_ih, bias_p, xg);
        lstm_rec<<<BB / 2, 256, 0, stream>>>(xg, Wp_hh_t, x_len, out);
    } else {
        lstm_rec_fused<<<BB / 2, 256, 0, stream>>>(x, Wp_ih_t, Wp_hh_t,
                                                   bias_p, x_len, out);
    }
}

// Round 3
// 2674.247 us; speedup vs baseline: 4.8858x; 4.8858x over previous
//
#include <hip/hip_runtime.h>
#include <hip/hip_fp16.h>
#include <math.h>

#define BB 128
#define TT 512
#define DD 256
#define HH 256
#define NG 1024  // 4*H

typedef _Float16 h2_t __attribute__((ext_vector_type(2)));

#if __has_builtin(__builtin_amdgcn_fdot2)
__device__ __forceinline__ float fdot2_(h2_t a, h2_t b, float c) {
    return __builtin_amdgcn_fdot2(a, b, c, false);
}
#else
__device__ __forceinline__ float fdot2_(h2_t a, h2_t b, float c) {
    return c + (float)a.x * (float)b.x + (float)a.y * (float)b.y;
}
#endif

__device__ __forceinline__ float sigmoidf_(float x) {
    return 1.0f / (1.0f + __expf(-x));
}
__device__ __forceinline__ float tanhf_(float x) {
    x = fminf(15.0f, fmaxf(-15.0f, x));
    float e = __expf(2.0f * x);
    return (e - 1.0f) / (e + 1.0f);
}

// Pack: packed col n = j*4+q <-> gate row g = q*256+j  (q: 0=i,1=f,2=g,3=o)
//  Wih32 [n][k] fp32 (GEMM)
//  Wh16/Wi16: fp16, k-pair-major: halfs at ((k>>1)*1024 + n)*2 + (k&1)
//  bias_p[n] = b_ih[g] + b_hh[g]
__global__ void pack2(const float* __restrict__ W_ih, const float* __restrict__ W_hh,
                      const float* __restrict__ b_ih, const float* __restrict__ b_hh,
                      float* __restrict__ Wih32, __half* __restrict__ Wi16,
                      __half* __restrict__ Wh16, float* __restrict__ bias_p) {
    int idx = blockIdx.x * 256 + threadIdx.x;   // 0..262143
    int n = idx >> 8;
    int k = idx & 255;
    int g = (n & 3) * 256 + (n >> 2);
    float wih = W_ih[g * 256 + k];
    float whh = W_hh[g * 256 + k];
    Wih32[n * 256 + k] = wih;
    size_t hidx = ((size_t)(k >> 1) * 1024 + n) * 2 + (k & 1);
    Wi16[hidx] = __float2half(wih);
    Wh16[hidx] = __float2half(whh);
    if (idx < 1024) {
        int gg = (idx & 3) * 256 + (idx >> 2);
        bias_p[idx] = b_ih[gg] + b_hh[gg];
    }
}

// xg chunk GEMM: rows m = b*Tc + tt (chunk-local), x row = b*512 + t0 + tt.
// M = 128*Tc, N = 1024, K = 256. BM=BN=64, BK=16, 256 thr, 4x4/thr.
__global__ __launch_bounds__(256) void xg_gemm(const float* __restrict__ X,
                                               const float* __restrict__ Wp,
                                               const float* __restrict__ bias_p,
                                               float* __restrict__ xg,
                                               int t0, int lTc, int tcMask) {
    __shared__ float As[16][68];
    __shared__ float Bs[16][68];
    int tid = threadIdx.x;
    int m0 = blockIdx.x * 64;
    int n0 = blockIdx.y * 64;
    int row = tid >> 2, kq = tid & 3;
    int tx = tid & 15, ty = tid >> 4;
    int mrow = m0 + row;
    size_t xrow = (size_t)(mrow >> lTc) * 512 + t0 + (mrow & tcMask);
    float acc[4][4];
#pragma unroll
    for (int i = 0; i < 4; ++i)
#pragma unroll
        for (int j = 0; j < 4; ++j) acc[i][j] = 0.0f;

    for (int k0 = 0; k0 < 256; k0 += 16) {
        float4 a = *(const float4*)&X[xrow * 256 + k0 + kq * 4];
        float4 b = *(const float4*)&Wp[(size_t)(n0 + row) * 256 + k0 + kq * 4];
        __syncthreads();
        As[kq * 4 + 0][row] = a.x; As[kq * 4 + 1][row] = a.y;
        As[kq * 4 + 2][row] = a.z; As[kq * 4 + 3][row] = a.w;
        Bs[kq * 4 + 0][row] = b.x; Bs[kq * 4 + 1][row] = b.y;
        Bs[kq * 4 + 2][row] = b.z; Bs[kq * 4 + 3][row] = b.w;
        __syncthreads();
#pragma unroll
        for (int k = 0; k < 16; ++k) {
            float4 ra = *(const float4*)&As[k][ty * 4];
            float4 rb = *(const float4*)&Bs[k][tx * 4];
            float va[4] = {ra.x, ra.y, ra.z, ra.w};
            float vb[4] = {rb.x, rb.y, rb.z, rb.w};
#pragma unroll
            for (int i = 0; i < 4; ++i)
#pragma unroll
                for (int j = 0; j < 4; ++j) acc[i][j] += va[i] * vb[j];
        }
    }
    float4 bias = *(const float4*)&bias_p[n0 + tx * 4];
#pragma unroll
    for (int i = 0; i < 4; ++i) {
        float4 v;
        v.x = acc[i][0] + bias.x; v.y = acc[i][1] + bias.y;
        v.z = acc[i][2] + bias.z; v.w = acc[i][3] + bias.w;
        *(float4*)&xg[(size_t)(m0 + ty * 4 + i) * 1024 + n0 + tx * 4] = v;
    }
}

// Recurrence chunk: 128 blocks (1 sample each) x 1024 threads.
// Thread (c = tid&255, kh = tid>>8): computes 4 gates of h[c] over k-quarter kh.
// Weights fp16 streamed from L2 (dwordx4 = 4 cols x 1 k-pair), h fp16 in LDS,
// fp32 accumulate via v_dot2_f32_f16. 4-way k-split reduced through LDS.
__global__ __launch_bounds__(1024) void lstm_rec16(const float* __restrict__ xg,
                                                   const __half* __restrict__ Wh16,
                                                   const int* __restrict__ x_len,
                                                   float* __restrict__ out,
                                                   __half* __restrict__ h_state,
                                                   float* __restrict__ c_state,
                                                   int t0, int Tc) {
    __shared__ __half hs_h[256];
    __shared__ float4 part[3][256];
    int tid = threadIdx.x;
    int c = tid & 255, kh = tid >> 8;     // kh in [0,4), wave-uniform
    int b = blockIdx.x;
    int len = x_len[b];
    float cst = 0.0f;
    if (kh == 0) {
        if (t0 == 0) {
            hs_h[c] = __float2half(0.0f);
        } else {
            hs_h[c] = h_state[b * 256 + c];
            cst = c_state[b * 256 + c];
        }
    }
    __syncthreads();
    // thread's weight base: k-pair p = kh*32 + i, halfs at (p*1024 + 4c)*2
    const uint4* wp = (const uint4*)(Wh16 + (size_t)(kh * 32) * 2048 + 8 * c);
    const float4* xgb = (const float4*)(xg + (size_t)b * Tc * 1024) + c;
    float* outb = out + ((size_t)b * 512 + t0) * 256 + c;

    for (int tt = 0; tt < Tc; ++tt) {
        float4 xgv;
        if (kh == 0) xgv = xgb[(size_t)tt * 256];
        float4 acc = {0.0f, 0.0f, 0.0f, 0.0f};
#pragma unroll 8
        for (int i = 0; i < 32; ++i) {
            uint4 u = wp[(size_t)i * 256];           // 16B: 4 cols, 1 k-pair
            h2_t hv = ((const h2_t*)hs_h)[kh * 32 + i];
            acc.x = fdot2_(__builtin_bit_cast(h2_t, u.x), hv, acc.x);
            acc.y = fdot2_(__builtin_bit_cast(h2_t, u.y), hv, acc.y);
            acc.z = fdot2_(__builtin_bit_cast(h2_t, u.z), hv, acc.z);
            acc.w = fdot2_(__builtin_bit_cast(h2_t, u.w), hv, acc.w);
        }
        if (kh) part[kh - 1][c] = acc;
        __syncthreads();
        if (kh == 0) {
            float4 p0 = part[0][c], p1 = part[1][c], p2 = part[2][c];
            float gi = acc.x + p0.x + p1.x + p2.x + xgv.x;
            float gf = acc.y + p0.y + p1.y + p2.y + xgv.y;
            float gg = acc.z + p0.z + p1.z + p2.z + xgv.z;
            float go = acc.w + p0.w + p1.w + p2.w + xgv.w;
            float iv = sigmoidf_(gi), fv = sigmoidf_(gf);
            float gv = tanhf_(gg),   ov = sigmoidf_(go);
            cst = fv * cst + iv * gv;
            float h = ov * tanhf_(cst);
            int t = t0 + tt;
            outb[(size_t)tt * 256] = (t < len) ? h : 0.0f;
            hs_h[c] = __float2half(h);
        }
        __syncthreads();
    }
    if (kh == 0) {
        h_state[b * 256 + c] = hs_h[c];
        c_state[b * 256 + c] = cst;
    }
}

// Fallback (ws too small for any xg chunk): fused, streams both fp16 matrices.
__global__ __launch_bounds__(1024) void lstm_fused16(const float* __restrict__ X,
                                                     const __half* __restrict__ Wi16,
                                                     const __half* __restrict__ Wh16,
                                                     const float* __restrict__ bias_p,
                                                     const int* __restrict__ x_len,
                                                     float* __restrict__ out) {
    __shared__ __half hs_h[256];
    __shared__ __half xs_h[256];
    __shared__ float4 part[3][256];
    int tid = threadIdx.x;
    int c = tid & 255, kh = tid >> 8;
    int b = blockIdx.x;
    int len = x_len[b];
    float cst = 0.0f;
    float4 bias;
    if (kh == 0) {
        bias = *(const float4*)&bias_p[4 * c];
        hs_h[c] = __float2half(0.0f);
    }
    const uint4* wph = (const uint4*)(Wh16 + (size_t)(kh * 32) * 2048 + 8 * c);
    const uint4* wpi = (const uint4*)(Wi16 + (size_t)(kh * 32) * 2048 + 8 * c);
    float* outb = out + (size_t)b * 512 * 256 + c;
    __syncthreads();

    for (int t = 0; t < TT; ++t) {
        if (tid < 128) {
            float2 xv = *(const float2*)&X[((size_t)b * 512 + t) * 256 + 2 * tid];
            h2_t xh = {(_Float16)xv.x, (_Float16)xv.y};
            ((h2_t*)xs_h)[tid] = xh;
        }
        __syncthreads();
        float4 acc = {0.0f, 0.0f, 0.0f, 0.0f};
#pragma unroll 4
        for (int i = 0; i < 32; ++i) {
            uint4 uh = wph[(size_t)i * 256];
            uint4 ui = wpi[(size_t)i * 256];
            h2_t hv = ((const h2_t*)hs_h)[kh * 32 + i];
            h2_t xv = ((const h2_t*)xs_h)[kh * 32 + i];
            acc.x = fdot2_(__builtin_bit_cast(h2_t, uh.x), hv, acc.x);
            acc.y = fdot2_(__builtin_bit_cast(h2_t, uh.y), hv, acc.y);
            acc.z = fdot2_(__builtin_bit_cast(h2_t, uh.z), hv, acc.z);
            acc.w = fdot2_(__builtin_bit_cast(h2_t, uh.w), hv, acc.w);
            acc.x = fdot2_(__builtin_bit_cast(h2_t, ui.x), xv, acc.x);
            acc.y = fdot2_(__builtin_bit_cast(h2_t, ui.y), xv, acc.y);
            acc.z = fdot2_(__builtin_bit_cast(h2_t, ui.z), xv, acc.z);
            acc.w = fdot2_(__builtin_bit_cast(h2_t, ui.w), xv, acc.w);
        }
        if (kh) part[kh - 1][c] = acc;
        __syncthreads();
        if (kh == 0) {
            float4 p0 = part[0][c], p1 = part[1][c], p2 = part[2][c];
            float gi = acc.x + p0.x + p1.x + p2.x + bias.x;
            float gf = acc.y + p0.y + p1.y + p2.y + bias.y;
            float gg = acc.z + p0.z + p1.z + p2.z + bias.z;
            float go = acc.w + p0.w + p1.w + p2.w + bias.w;
            float iv = sigmoidf_(gi), fv = sigmoidf_(gf);
            float gv = tanhf_(gg),   ov = sigmoidf_(go);
            cst = fv * cst + iv * gv;
            float h = ov * tanhf_(cst);
            outb[(size_t)t * 256] = (t < len) ? h : 0.0f;
            hs_h[c] = __float2half(h);
        }
        __syncthreads();
    }
}

extern "C" void kernel_launch(void* const* d_in, const int* in_sizes, int n_in,
                              void* d_out, int out_size, void* d_ws, size_t ws_size,
                              hipStream_t stream) {
    const float* x     = (const float*)d_in[0];
    const int*   x_len = (const int*)d_in[1];
    const float* W_ih  = (const float*)d_in[2];
    const float* W_hh  = (const float*)d_in[3];
    const float* b_ih  = (const float*)d_in[4];
    const float* b_hh  = (const float*)d_in[5];
    float* out = (float*)d_out;

    char* ws = (char*)d_ws;
    float*  Wih32   = (float*)ws;                                  // 1 MB
    __half* Wh16    = (__half*)(ws + (1u << 20));                  // 512 KB
    __half* Wi16    = (__half*)(ws + (1u << 20) + (1u << 19));     // 512 KB
    float*  bias_p  = (float*)(ws + (2u << 20));                   // 4 KB
    __half* h_state = (__half*)(ws + (2u << 20) + 4096);           // 64 KB
    float*  c_state = (float*)(ws + (2u << 20) + 4096 + 65536);    // 128 KB
    size_t  o_xg    = (size_t)(2u << 20) + 4096 + 65536 + 131072;
    float*  xg      = (float*)(ws + o_xg);

    int Tc = 0;
    for (int cand = 512; cand >= 16; cand >>= 1)
        if (ws_size >= o_xg + (size_t)cand * 524288) { Tc = cand; break; }

    pack2<<<1024, 256, 0, stream>>>(W_ih, W_hh, b_ih, b_hh,
                                    Wih32, Wi16, Wh16, bias_p);
    if (Tc) {
        int lTc = 31 - __builtin_clz((unsigned)Tc);
        for (int t0 = 0; t0 < TT; t0 += Tc) {
            dim3 g(2 * Tc, 16);   // (128*Tc/64, 1024/64)
            xg_gemm<<<g, 256, 0, stream>>>(x, Wih32, bias_p, xg, t0, lTc, Tc - 1);
            lstm_rec16<<<BB, 1024, 0, stream>>>(xg, Wh16, x_len, out,
                                                h_state, c_state, t0, Tc);
        }
    } else {
        lstm_fused16<<<BB, 1024, 0, stream>>>(x, Wi16, Wh16, bias_p, x_len, out);
    }
}